// Round 9
// baseline (125.111 us; speedup 1.0000x reference)
//
#include <hip/hip_runtime.h>

// MLPDecoder: out[e, c] = sum_d |input[r[e],d] - input[c[e],d]| * W[d,c]
// N_NODES=100000, D=256, N_EDGES=500000, N_CLASSES=4
//
// R9: make the random gathers L2-HITS. R5-R8 showed the cost is the L2-miss
// path (~1.8M line fills/dispatch; ILP-invariant 76-97us). The int8 table
// (25.6MB) exceeds a 4MB XCD L2, but a 32-dim slice (3.2MB dense) fits.
//   k1: quant fp32 -> biased uint8, stored TRANSPOSED tbl_t[8][NODES][32B]
//       (dense per slice; strided slices would set-alias in L2).
//   k2: block b -> slice b&7 (blockIdx round-robins over the 8 XCDs, so each
//       XCD's L2 caches only its own 3.2MB slice + 0.4MB scales). 4-lane
//       group per edge-slice, 8 dims/lane via uint2, x2 edge unroll,
//       2-stage butterfly; writes f32 partials part[8][E][4] in d_ws.
//   k3: out[e] = sum_s part[s][e]  (64MB read, L3-resident).
// Accuracy: same int8 math as R5-R8 (absmax 0.082 < 0.143).
// Fallbacks: R8 flat path if ws < 90.4MB; f32 direct if ws < 26MB.

#define NODES   100000
#define DIM     256
#define EDGES   500000   // divisible by 4
#define NCLS    4
#define NSLICE  8
#define SLB     32       // bytes (=dims) per node per slice

// ---------------- k1: quantize to biased uint8, transposed layout ----------------
__global__ __launch_bounds__(256) void quant_t_kernel(
    const float* __restrict__ in,        // [NODES, DIM]
    unsigned char* __restrict__ tbl_t,   // [NSLICE][NODES][SLB]
    float* __restrict__ scales)          // [NODES]
{
    const int lane = threadIdx.x & 63;
    const int wid  = (blockIdx.x * blockDim.x + threadIdx.x) >> 6;
    const int n_waves = (gridDim.x * blockDim.x) >> 6;

    const int s   = lane >> 3;           // slice this lane's 4 dims belong to
    const int off = (lane & 7) * 4;      // byte offset within the 32B record

    for (int row = wid; row < NODES; row += n_waves) {
        const float4 v = *(const float4*)(in + (size_t)row * DIM + lane * 4);
        float m = fmaxf(fmaxf(fabsf(v.x), fabsf(v.y)),
                        fmaxf(fabsf(v.z), fabsf(v.w)));
        #pragma unroll
        for (int sh = 32; sh >= 1; sh >>= 1)
            m = fmaxf(m, __shfl_xor(m, sh, 64));

        const float rs = (m > 0.f) ? 127.f / m : 0.f;
        uchar4 q;
        q.x = (unsigned char)__float2int_rn(fmaf(v.x, rs, 128.f));
        q.y = (unsigned char)__float2int_rn(fmaf(v.y, rs, 128.f));
        q.z = (unsigned char)__float2int_rn(fmaf(v.z, rs, 128.f));
        q.w = (unsigned char)__float2int_rn(fmaf(v.w, rs, 128.f));
        *(uchar4*)(tbl_t + ((size_t)s * NODES + row) * SLB + off) = q;

        if (lane == 0) scales[row] = (m > 0.f) ? m / 127.f : 0.f;
    }
}

// ---------------- k2: sliced gather -> partials ----------------
__global__ __launch_bounds__(256, 6) void edge_mlp_sliced_kernel(
    const unsigned char* __restrict__ tbl_t,  // [NSLICE][NODES][SLB]
    const float* __restrict__ scales,         // [NODES]
    const int*   __restrict__ r_idx,          // [EDGES]
    const int*   __restrict__ c_idx,          // [EDGES]
    const float* __restrict__ weight,         // [DIM, NCLS]
    float*       __restrict__ part)           // [NSLICE][EDGES][NCLS]
{
    const int slice = blockIdx.x & 7;         // -> XCD (round-robin dispatch)
    const int sb    = blockIdx.x >> 3;        // 0..255 block within slice
    const int g     = threadIdx.x >> 2;       // 0..63 group in block
    const int gl    = threadIdx.x & 3;        // lane in group

    const unsigned char* base = tbl_t + (size_t)slice * NODES * SLB;
    float* pbase = part + (size_t)slice * EDGES * NCLS;

    // This lane covers dims [slice*32 + gl*8, +8).
    const int d0 = slice * 32 + gl * 8;
    float4 w[8];
    #pragma unroll
    for (int j = 0; j < 8; ++j)
        w[j] = *(const float4*)(weight + (d0 + j) * NCLS);

    const int e0   = (sb * 64 + g) * 2;
    const int step = 256 * 64 * 2;            // 32768

    for (int e = e0; e < EDGES; e += step) {
        const int eA = e, eB = e + 1;         // EDGES even -> eB < EDGES

        // Independent batch of loads (idx -> scales+rows; 2 edges).
        const int rA = r_idx[eA], cA = c_idx[eA];
        const int rB = r_idx[eB], cB = c_idx[eB];

        const float srA = scales[rA], scA = scales[cA];
        const float srB = scales[rB], scB = scales[cB];
        const uint2 uaA = *(const uint2*)(base + (size_t)rA * SLB + gl * 8);
        const uint2 ubA = *(const uint2*)(base + (size_t)cA * SLB + gl * 8);
        const uint2 uaB = *(const uint2*)(base + (size_t)rB * SLB + gl * 8);
        const uint2 ubB = *(const uint2*)(base + (size_t)cB * SLB + gl * 8);

        float u, t;
        #define TERM(UA, UB, SH, W, SR, NSC, BB, ACC)                        \
            u = fmaf((float)((UA >> SH) & 0xffu), SR,                        \
                     fmaf((float)((UB >> SH) & 0xffu), NSC, BB));            \
            t = fabsf(u);                                                    \
            ACC.x = fmaf(t, W.x, ACC.x);                                     \
            ACC.y = fmaf(t, W.y, ACC.y);                                     \
            ACC.z = fmaf(t, W.z, ACC.z);                                     \
            ACC.w = fmaf(t, W.w, ACC.w);

        const float nscA = -scA;
        const float BA = 128.f * (scA - srA);
        float4 accA = make_float4(0.f, 0.f, 0.f, 0.f);
        TERM(uaA.x, ubA.x,  0, w[0], srA, nscA, BA, accA)
        TERM(uaA.x, ubA.x,  8, w[1], srA, nscA, BA, accA)
        TERM(uaA.x, ubA.x, 16, w[2], srA, nscA, BA, accA)
        TERM(uaA.x, ubA.x, 24, w[3], srA, nscA, BA, accA)
        TERM(uaA.y, ubA.y,  0, w[4], srA, nscA, BA, accA)
        TERM(uaA.y, ubA.y,  8, w[5], srA, nscA, BA, accA)
        TERM(uaA.y, ubA.y, 16, w[6], srA, nscA, BA, accA)
        TERM(uaA.y, ubA.y, 24, w[7], srA, nscA, BA, accA)

        const float nscB = -scB;
        const float BB2 = 128.f * (scB - srB);
        float4 accB = make_float4(0.f, 0.f, 0.f, 0.f);
        TERM(uaB.x, ubB.x,  0, w[0], srB, nscB, BB2, accB)
        TERM(uaB.x, ubB.x,  8, w[1], srB, nscB, BB2, accB)
        TERM(uaB.x, ubB.x, 16, w[2], srB, nscB, BB2, accB)
        TERM(uaB.x, ubB.x, 24, w[3], srB, nscB, BB2, accB)
        TERM(uaB.y, ubB.y,  0, w[4], srB, nscB, BB2, accB)
        TERM(uaB.y, ubB.y,  8, w[5], srB, nscB, BB2, accB)
        TERM(uaB.y, ubB.y, 16, w[6], srB, nscB, BB2, accB)
        TERM(uaB.y, ubB.y, 24, w[7], srB, nscB, BB2, accB)
        #undef TERM

        // Reduce across the 4-lane group (xor 1,2 stay in-group).
        #pragma unroll
        for (int m = 2; m >= 1; m >>= 1) {
            accA.x += __shfl_xor(accA.x, m, 64);
            accB.x += __shfl_xor(accB.x, m, 64);
            accA.y += __shfl_xor(accA.y, m, 64);
            accB.y += __shfl_xor(accB.y, m, 64);
            accA.z += __shfl_xor(accA.z, m, 64);
            accB.z += __shfl_xor(accB.z, m, 64);
            accA.w += __shfl_xor(accA.w, m, 64);
            accB.w += __shfl_xor(accB.w, m, 64);
        }

        if (gl == 0) {
            *(float4*)(pbase + (size_t)eA * NCLS) = accA;
            *(float4*)(pbase + (size_t)eB * NCLS) = accB;
        }
    }
}

// ---------------- k3: sum partials across slices ----------------
__global__ __launch_bounds__(256) void reduce_part_kernel(
    const float* __restrict__ part,      // [NSLICE][EDGES][NCLS]
    float*       __restrict__ out)       // [EDGES][NCLS]
{
    const int e = blockIdx.x * blockDim.x + threadIdx.x;
    if (e >= EDGES) return;
    float4 s = make_float4(0.f, 0.f, 0.f, 0.f);
    #pragma unroll
    for (int sl = 0; sl < NSLICE; ++sl) {
        const float4 p = *(const float4*)(part + ((size_t)sl * EDGES + e) * NCLS);
        s.x += p.x; s.y += p.y; s.z += p.z; s.w += p.w;
    }
    *(float4*)(out + (size_t)e * NCLS) = s;
}

// ---------------- fallback A: flat quant (R5) ----------------
__global__ __launch_bounds__(256) void quant_kernel(
    const float* __restrict__ in,
    unsigned char* __restrict__ tbl,
    float* __restrict__ scales)
{
    const int lane = threadIdx.x & 63;
    const int wid  = (blockIdx.x * blockDim.x + threadIdx.x) >> 6;
    const int n_waves = (gridDim.x * blockDim.x) >> 6;

    for (int row = wid; row < NODES; row += n_waves) {
        const float4 v = *(const float4*)(in + (size_t)row * DIM + lane * 4);
        float m = fmaxf(fmaxf(fabsf(v.x), fabsf(v.y)),
                        fmaxf(fabsf(v.z), fabsf(v.w)));
        #pragma unroll
        for (int s = 32; s >= 1; s >>= 1)
            m = fmaxf(m, __shfl_xor(m, s, 64));

        const float rs = (m > 0.f) ? 127.f / m : 0.f;
        uchar4 q;
        q.x = (unsigned char)__float2int_rn(fmaf(v.x, rs, 128.f));
        q.y = (unsigned char)__float2int_rn(fmaf(v.y, rs, 128.f));
        q.z = (unsigned char)__float2int_rn(fmaf(v.z, rs, 128.f));
        q.w = (unsigned char)__float2int_rn(fmaf(v.w, rs, 128.f));
        *(uchar4*)(tbl + (size_t)row * DIM + lane * 4) = q;

        if (lane == 0) scales[row] = (m > 0.f) ? m / 127.f : 0.f;
    }
}

// ---------------- fallback A: R8 x2 flat gather ----------------
__global__ __launch_bounds__(256, 6) void edge_mlp_i8_x2_kernel(
    const unsigned char* __restrict__ tbl,
    const float* __restrict__ scales,
    const int*   __restrict__ r_idx,
    const int*   __restrict__ c_idx,
    const float* __restrict__ weight,
    float*       __restrict__ out)
{
    const int lane = threadIdx.x & 63;
    const int half = lane >> 5;
    const int hl   = lane & 31;
    const int wid  = (blockIdx.x * blockDim.x + threadIdx.x) >> 6;
    const int n_waves = (gridDim.x * blockDim.x) >> 6;
    const int step = n_waves * 4;

    const int d0 = hl * 8;
    float4 w[8];
    #pragma unroll
    for (int j = 0; j < 8; ++j)
        w[j] = *(const float4*)(weight + (d0 + j) * NCLS);

    for (int e = wid * 4; e < EDGES; e += step) {
        const int eeA = e + half;
        const int eeB = e + 2 + half;

        const int rA = r_idx[eeA], cA = c_idx[eeA];
        const int rB = r_idx[eeB], cB = c_idx[eeB];

        const float srA = scales[rA], scA = scales[cA];
        const float srB = scales[rB], scB = scales[cB];
        const uint2 uaA = *(const uint2*)(tbl + (size_t)rA * DIM + d0);
        const uint2 ubA = *(const uint2*)(tbl + (size_t)cA * DIM + d0);
        const uint2 uaB = *(const uint2*)(tbl + (size_t)rB * DIM + d0);
        const uint2 ubB = *(const uint2*)(tbl + (size_t)cB * DIM + d0);

        float u, t;
        #define TERM(UA, UB, SH, W, SR, NSC, BB, ACC)                        \
            u = fmaf((float)((UA >> SH) & 0xffu), SR,                        \
                     fmaf((float)((UB >> SH) & 0xffu), NSC, BB));            \
            t = fabsf(u);                                                    \
            ACC.x = fmaf(t, W.x, ACC.x);                                     \
            ACC.y = fmaf(t, W.y, ACC.y);                                     \
            ACC.z = fmaf(t, W.z, ACC.z);                                     \
            ACC.w = fmaf(t, W.w, ACC.w);

        const float nscA = -scA;
        const float BA = 128.f * (scA - srA);
        float4 accA = make_float4(0.f, 0.f, 0.f, 0.f);
        TERM(uaA.x, ubA.x,  0, w[0], srA, nscA, BA, accA)
        TERM(uaA.x, ubA.x,  8, w[1], srA, nscA, BA, accA)
        TERM(uaA.x, ubA.x, 16, w[2], srA, nscA, BA, accA)
        TERM(uaA.x, ubA.x, 24, w[3], srA, nscA, BA, accA)
        TERM(uaA.y, ubA.y,  0, w[4], srA, nscA, BA, accA)
        TERM(uaA.y, ubA.y,  8, w[5], srA, nscA, BA, accA)
        TERM(uaA.y, ubA.y, 16, w[6], srA, nscA, BA, accA)
        TERM(uaA.y, ubA.y, 24, w[7], srA, nscA, BA, accA)

        const float nscB = -scB;
        const float BB = 128.f * (scB - srB);
        float4 accB = make_float4(0.f, 0.f, 0.f, 0.f);
        TERM(uaB.x, ubB.x,  0, w[0], srB, nscB, BB, accB)
        TERM(uaB.x, ubB.x,  8, w[1], srB, nscB, BB, accB)
        TERM(uaB.x, ubB.x, 16, w[2], srB, nscB, BB, accB)
        TERM(uaB.x, ubB.x, 24, w[3], srB, nscB, BB, accB)
        TERM(uaB.y, ubB.y,  0, w[4], srB, nscB, BB, accB)
        TERM(uaB.y, ubB.y,  8, w[5], srB, nscB, BB, accB)
        TERM(uaB.y, ubB.y, 16, w[6], srB, nscB, BB, accB)
        TERM(uaB.y, ubB.y, 24, w[7], srB, nscB, BB, accB)
        #undef TERM

        #pragma unroll
        for (int m = 16; m >= 1; m >>= 1) {
            accA.x += __shfl_xor(accA.x, m, 64);
            accB.x += __shfl_xor(accB.x, m, 64);
            accA.y += __shfl_xor(accA.y, m, 64);
            accB.y += __shfl_xor(accB.y, m, 64);
            accA.z += __shfl_xor(accA.z, m, 64);
            accB.z += __shfl_xor(accB.z, m, 64);
            accA.w += __shfl_xor(accA.w, m, 64);
            accB.w += __shfl_xor(accB.w, m, 64);
        }

        if (hl == 0) {
            *(float4*)(out + (size_t)eeA * NCLS) = accA;
            *(float4*)(out + (size_t)eeB * NCLS) = accB;
        }
    }
}

// ---------------- fallback B: fp32 wave-per-edge ----------------
__global__ __launch_bounds__(256, 8) void edge_mlp_f32_kernel(
    const float* __restrict__ input,
    const int*   __restrict__ r_idx,
    const int*   __restrict__ c_idx,
    const float* __restrict__ weight,
    float*       __restrict__ out)
{
    const int lane = threadIdx.x & 63;
    const int wid  = (blockIdx.x * blockDim.x + threadIdx.x) >> 6;
    const int n_waves = (gridDim.x * blockDim.x) >> 6;

    const int d0 = lane * 4;
    const float4 w0 = *(const float4*)(weight + (d0 + 0) * NCLS);
    const float4 w1 = *(const float4*)(weight + (d0 + 1) * NCLS);
    const float4 w2 = *(const float4*)(weight + (d0 + 2) * NCLS);
    const float4 w3 = *(const float4*)(weight + (d0 + 3) * NCLS);

    for (int e = wid; e < EDGES; e += n_waves) {
        const int r = r_idx[e];
        const int c = c_idx[e];
        const float4 a = *(const float4*)(input + (size_t)r * DIM + d0);
        const float4 b = *(const float4*)(input + (size_t)c * DIM + d0);

        const float t0 = fabsf(a.x - b.x);
        const float t1 = fabsf(a.y - b.y);
        const float t2 = fabsf(a.z - b.z);
        const float t3 = fabsf(a.w - b.w);

        float4 acc;
        acc.x = t0 * w0.x + t1 * w1.x + t2 * w2.x + t3 * w3.x;
        acc.y = t0 * w0.y + t1 * w1.y + t2 * w2.y + t3 * w3.y;
        acc.z = t0 * w0.z + t1 * w1.z + t2 * w2.z + t3 * w3.z;
        acc.w = t0 * w0.w + t1 * w1.w + t2 * w2.w + t3 * w3.w;

        #pragma unroll
        for (int m = 32; m >= 1; m >>= 1) {
            acc.x += __shfl_xor(acc.x, m, 64);
            acc.y += __shfl_xor(acc.y, m, 64);
            acc.z += __shfl_xor(acc.z, m, 64);
            acc.w += __shfl_xor(acc.w, m, 64);
        }
        if (lane == 0) *(float4*)(out + (size_t)e * NCLS) = acc;
    }
}

extern "C" void kernel_launch(void* const* d_in, const int* in_sizes, int n_in,
                              void* d_out, int out_size, void* d_ws, size_t ws_size,
                              hipStream_t stream) {
    const float* input  = (const float*)d_in[0];
    const int*   r_idx  = (const int*)d_in[1];
    const int*   c_idx  = (const int*)d_in[2];
    const float* weight = (const float*)d_in[3];
    float* out = (float*)d_out;

    const size_t tbl_bytes   = (size_t)NODES * DIM;                 // 25.6 MB
    const size_t scale_bytes = (size_t)NODES * sizeof(float);       // 0.4 MB
    const size_t part_off    = (tbl_bytes + scale_bytes + 255) & ~(size_t)255;
    const size_t part_bytes  = (size_t)NSLICE * EDGES * NCLS * 4;   // 64 MB
    const size_t sliced_need = part_off + part_bytes;               // ~90.4 MB

    if (ws_size >= sliced_need) {
        unsigned char* tbl_t = (unsigned char*)d_ws;
        float* scales = (float*)((char*)d_ws + tbl_bytes);
        float* part   = (float*)((char*)d_ws + part_off);
        quant_t_kernel<<<2048, 256, 0, stream>>>(input, tbl_t, scales);
        edge_mlp_sliced_kernel<<<2048, 256, 0, stream>>>(tbl_t, scales, r_idx,
                                                         c_idx, weight, part);
        reduce_part_kernel<<<(EDGES + 255) / 256, 256, 0, stream>>>(part, out);
    } else if (ws_size >= tbl_bytes + scale_bytes) {
        unsigned char* tbl = (unsigned char*)d_ws;
        float* scales = (float*)((char*)d_ws + tbl_bytes);
        quant_kernel<<<2048, 256, 0, stream>>>(input, tbl, scales);
        edge_mlp_i8_x2_kernel<<<2048, 256, 0, stream>>>(tbl, scales, r_idx,
                                                        c_idx, weight, out);
    } else {
        edge_mlp_f32_kernel<<<2048, 256, 0, stream>>>(input, r_idx, c_idx,
                                                      weight, out);
    }
}

// Round 10
// 98.267 us; speedup vs baseline: 1.2732x; 1.2732x over previous
//
#include <hip/hip_runtime.h>

// MLPDecoder: out[e, c] = sum_d |input[r[e],d] - input[c[e],d]| * W[d,c]
// N_NODES=100000, D=256, N_EDGES=500000, N_CLASSES=4
//
// R10: R8's proven flat-int8 gather + PER-EDGE RECORD precompute.
// R9 taught: L2-hit slicing raises request count faster than it cuts cost.
// R8's real limiter is the per-iteration serial chain idx->scale->row->compute
// (only ~12 outstanding row reqs/CU by Little's law). R10 hoists idx+scale
// into a streaming pass:
//   k1: per-row absmax -> biased uint8 quantize, scale[row]=m/127 (as R5).
//   k2: rec[e] = {r*256, c*256, sr_bits, sc_bits} (uint4, 8MB, coalesced
//       write; scale gathers hit the L2-hot 400KB array).
//   k3: gather: rec (streamed) -> rows -> compute. Half-wave per edge,
//       lane=8 dims via uint2, x2 edge unroll, 5-stage butterfly.
// Math identical to R5-R8: absmax 0.08203125 < 0.143.
// Fallbacks: R8 path (ws >= 26MB), f32 direct (else).

#define NODES   100000
#define DIM     256
#define EDGES   500000   // divisible by 4
#define NCLS    4

// ---------------- k1: per-row quantize to biased uint8 ----------------
__global__ __launch_bounds__(256) void quant_kernel(
    const float* __restrict__ in,        // [NODES, DIM]
    unsigned char* __restrict__ tbl,     // [NODES, DIM] biased uint8
    float* __restrict__ scales)          // [NODES]
{
    const int lane = threadIdx.x & 63;
    const int wid  = (blockIdx.x * blockDim.x + threadIdx.x) >> 6;
    const int n_waves = (gridDim.x * blockDim.x) >> 6;

    for (int row = wid; row < NODES; row += n_waves) {
        const float4 v = *(const float4*)(in + (size_t)row * DIM + lane * 4);
        float m = fmaxf(fmaxf(fabsf(v.x), fabsf(v.y)),
                        fmaxf(fabsf(v.z), fabsf(v.w)));
        #pragma unroll
        for (int s = 32; s >= 1; s >>= 1)
            m = fmaxf(m, __shfl_xor(m, s, 64));

        const float rs = (m > 0.f) ? 127.f / m : 0.f;
        uchar4 q;
        q.x = (unsigned char)__float2int_rn(fmaf(v.x, rs, 128.f));
        q.y = (unsigned char)__float2int_rn(fmaf(v.y, rs, 128.f));
        q.z = (unsigned char)__float2int_rn(fmaf(v.z, rs, 128.f));
        q.w = (unsigned char)__float2int_rn(fmaf(v.w, rs, 128.f));
        *(uchar4*)(tbl + (size_t)row * DIM + lane * 4) = q;

        if (lane == 0) scales[row] = (m > 0.f) ? m / 127.f : 0.f;
    }
}

// ---------------- k2: per-edge record build ----------------
__global__ __launch_bounds__(256) void rec_kernel(
    const int*   __restrict__ r_idx,     // [EDGES]
    const int*   __restrict__ c_idx,     // [EDGES]
    const float* __restrict__ scales,    // [NODES]
    uint4*       __restrict__ recs)      // [EDGES] {r*256, c*256, sr, sc}
{
    const int stride = gridDim.x * blockDim.x;
    for (int e = blockIdx.x * blockDim.x + threadIdx.x; e < EDGES; e += stride) {
        const int r = r_idx[e];
        const int c = c_idx[e];
        uint4 rec;
        rec.x = (unsigned)r * DIM;               // byte offset (1B/elem)
        rec.y = (unsigned)c * DIM;
        rec.z = __float_as_uint(scales[r]);
        rec.w = __float_as_uint(scales[c]);
        recs[e] = rec;
    }
}

// ---------------- k3: gather with records, x2 unroll ----------------
__global__ __launch_bounds__(256, 6) void edge_mlp_i8_rec_kernel(
    const unsigned char* __restrict__ tbl,   // [NODES*DIM] biased uint8
    const uint4* __restrict__ recs,          // [EDGES]
    const float* __restrict__ weight,        // [DIM, NCLS]
    float*       __restrict__ out)           // [EDGES, NCLS]
{
    const int lane = threadIdx.x & 63;
    const int half = lane >> 5;          // which edge of each pair
    const int hl   = lane & 31;          // lane within half
    const int wid  = (blockIdx.x * blockDim.x + threadIdx.x) >> 6;
    const int n_waves = (gridDim.x * blockDim.x) >> 6;
    const int step = n_waves * 4;

    // This lane covers dims [8*hl, 8*hl+8).
    const int d0 = hl * 8;
    float4 w[8];
    #pragma unroll
    for (int j = 0; j < 8; ++j)
        w[j] = *(const float4*)(weight + (d0 + j) * NCLS);

    for (int e = wid * 4; e < EDGES; e += step) {
        // EDGES % 4 == 0 -> e+3 < EDGES whenever e < EDGES.
        const int eeA = e + half;
        const int eeB = e + 2 + half;

        // One 16B rec load per edge (broadcast within the half) -> then rows.
        const uint4 recA = recs[eeA];
        const uint4 recB = recs[eeB];

        const float srA = __uint_as_float(recA.z);
        const float scA = __uint_as_float(recA.w);
        const float srB = __uint_as_float(recB.z);
        const float scB = __uint_as_float(recB.w);

        const uint2 uaA = *(const uint2*)(tbl + recA.x + d0);
        const uint2 ubA = *(const uint2*)(tbl + recA.y + d0);
        const uint2 uaB = *(const uint2*)(tbl + recB.x + d0);
        const uint2 ubB = *(const uint2*)(tbl + recB.y + d0);

        float u, t;
        #define TERM(UA, UB, SH, W, SR, NSC, BB, ACC)                        \
            u = fmaf((float)((UA >> SH) & 0xffu), SR,                        \
                     fmaf((float)((UB >> SH) & 0xffu), NSC, BB));            \
            t = fabsf(u);                                                    \
            ACC.x = fmaf(t, W.x, ACC.x);                                     \
            ACC.y = fmaf(t, W.y, ACC.y);                                     \
            ACC.z = fmaf(t, W.z, ACC.z);                                     \
            ACC.w = fmaf(t, W.w, ACC.w);

        const float nscA = -scA;
        const float BA = 128.f * (scA - srA);
        float4 accA = make_float4(0.f, 0.f, 0.f, 0.f);
        TERM(uaA.x, ubA.x,  0, w[0], srA, nscA, BA, accA)
        TERM(uaA.x, ubA.x,  8, w[1], srA, nscA, BA, accA)
        TERM(uaA.x, ubA.x, 16, w[2], srA, nscA, BA, accA)
        TERM(uaA.x, ubA.x, 24, w[3], srA, nscA, BA, accA)
        TERM(uaA.y, ubA.y,  0, w[4], srA, nscA, BA, accA)
        TERM(uaA.y, ubA.y,  8, w[5], srA, nscA, BA, accA)
        TERM(uaA.y, ubA.y, 16, w[6], srA, nscA, BA, accA)
        TERM(uaA.y, ubA.y, 24, w[7], srA, nscA, BA, accA)

        const float nscB = -scB;
        const float BB = 128.f * (scB - srB);
        float4 accB = make_float4(0.f, 0.f, 0.f, 0.f);
        TERM(uaB.x, ubB.x,  0, w[0], srB, nscB, BB, accB)
        TERM(uaB.x, ubB.x,  8, w[1], srB, nscB, BB, accB)
        TERM(uaB.x, ubB.x, 16, w[2], srB, nscB, BB, accB)
        TERM(uaB.x, ubB.x, 24, w[3], srB, nscB, BB, accB)
        TERM(uaB.y, ubB.y,  0, w[4], srB, nscB, BB, accB)
        TERM(uaB.y, ubB.y,  8, w[5], srB, nscB, BB, accB)
        TERM(uaB.y, ubB.y, 16, w[6], srB, nscB, BB, accB)
        TERM(uaB.y, ubB.y, 24, w[7], srB, nscB, BB, accB)
        #undef TERM

        // Two interleaved butterflies within each 32-lane half.
        #pragma unroll
        for (int m = 16; m >= 1; m >>= 1) {
            accA.x += __shfl_xor(accA.x, m, 64);
            accB.x += __shfl_xor(accB.x, m, 64);
            accA.y += __shfl_xor(accA.y, m, 64);
            accB.y += __shfl_xor(accB.y, m, 64);
            accA.z += __shfl_xor(accA.z, m, 64);
            accB.z += __shfl_xor(accB.z, m, 64);
            accA.w += __shfl_xor(accA.w, m, 64);
            accB.w += __shfl_xor(accB.w, m, 64);
        }

        if (hl == 0) {
            *(float4*)(out + (size_t)eeA * NCLS) = accA;
            *(float4*)(out + (size_t)eeB * NCLS) = accB;
        }
    }
}

// ---------------- fallback A: R8 x2 flat gather (no recs) ----------------
__global__ __launch_bounds__(256, 6) void edge_mlp_i8_x2_kernel(
    const unsigned char* __restrict__ tbl,
    const float* __restrict__ scales,
    const int*   __restrict__ r_idx,
    const int*   __restrict__ c_idx,
    const float* __restrict__ weight,
    float*       __restrict__ out)
{
    const int lane = threadIdx.x & 63;
    const int half = lane >> 5;
    const int hl   = lane & 31;
    const int wid  = (blockIdx.x * blockDim.x + threadIdx.x) >> 6;
    const int n_waves = (gridDim.x * blockDim.x) >> 6;
    const int step = n_waves * 4;

    const int d0 = hl * 8;
    float4 w[8];
    #pragma unroll
    for (int j = 0; j < 8; ++j)
        w[j] = *(const float4*)(weight + (d0 + j) * NCLS);

    for (int e = wid * 4; e < EDGES; e += step) {
        const int eeA = e + half;
        const int eeB = e + 2 + half;

        const int rA = r_idx[eeA], cA = c_idx[eeA];
        const int rB = r_idx[eeB], cB = c_idx[eeB];

        const float srA = scales[rA], scA = scales[cA];
        const float srB = scales[rB], scB = scales[cB];
        const uint2 uaA = *(const uint2*)(tbl + (size_t)rA * DIM + d0);
        const uint2 ubA = *(const uint2*)(tbl + (size_t)cA * DIM + d0);
        const uint2 uaB = *(const uint2*)(tbl + (size_t)rB * DIM + d0);
        const uint2 ubB = *(const uint2*)(tbl + (size_t)cB * DIM + d0);

        float u, t;
        #define TERM(UA, UB, SH, W, SR, NSC, BB, ACC)                        \
            u = fmaf((float)((UA >> SH) & 0xffu), SR,                        \
                     fmaf((float)((UB >> SH) & 0xffu), NSC, BB));            \
            t = fabsf(u);                                                    \
            ACC.x = fmaf(t, W.x, ACC.x);                                     \
            ACC.y = fmaf(t, W.y, ACC.y);                                     \
            ACC.z = fmaf(t, W.z, ACC.z);                                     \
            ACC.w = fmaf(t, W.w, ACC.w);

        const float nscA = -scA;
        const float BA = 128.f * (scA - srA);
        float4 accA = make_float4(0.f, 0.f, 0.f, 0.f);
        TERM(uaA.x, ubA.x,  0, w[0], srA, nscA, BA, accA)
        TERM(uaA.x, ubA.x,  8, w[1], srA, nscA, BA, accA)
        TERM(uaA.x, ubA.x, 16, w[2], srA, nscA, BA, accA)
        TERM(uaA.x, ubA.x, 24, w[3], srA, nscA, BA, accA)
        TERM(uaA.y, ubA.y,  0, w[4], srA, nscA, BA, accA)
        TERM(uaA.y, ubA.y,  8, w[5], srA, nscA, BA, accA)
        TERM(uaA.y, ubA.y, 16, w[6], srA, nscA, BA, accA)
        TERM(uaA.y, ubA.y, 24, w[7], srA, nscA, BA, accA)

        const float nscB = -scB;
        const float BB = 128.f * (scB - srB);
        float4 accB = make_float4(0.f, 0.f, 0.f, 0.f);
        TERM(uaB.x, ubB.x,  0, w[0], srB, nscB, BB, accB)
        TERM(uaB.x, ubB.x,  8, w[1], srB, nscB, BB, accB)
        TERM(uaB.x, ubB.x, 16, w[2], srB, nscB, BB, accB)
        TERM(uaB.x, ubB.x, 24, w[3], srB, nscB, BB, accB)
        TERM(uaB.y, ubB.y,  0, w[4], srB, nscB, BB, accB)
        TERM(uaB.y, ubB.y,  8, w[5], srB, nscB, BB, accB)
        TERM(uaB.y, ubB.y, 16, w[6], srB, nscB, BB, accB)
        TERM(uaB.y, ubB.y, 24, w[7], srB, nscB, BB, accB)
        #undef TERM

        #pragma unroll
        for (int m = 16; m >= 1; m >>= 1) {
            accA.x += __shfl_xor(accA.x, m, 64);
            accB.x += __shfl_xor(accB.x, m, 64);
            accA.y += __shfl_xor(accA.y, m, 64);
            accB.y += __shfl_xor(accB.y, m, 64);
            accA.z += __shfl_xor(accA.z, m, 64);
            accB.z += __shfl_xor(accB.z, m, 64);
            accA.w += __shfl_xor(accA.w, m, 64);
            accB.w += __shfl_xor(accB.w, m, 64);
        }

        if (hl == 0) {
            *(float4*)(out + (size_t)eeA * NCLS) = accA;
            *(float4*)(out + (size_t)eeB * NCLS) = accB;
        }
    }
}

// ---------------- fallback B: fp32 wave-per-edge ----------------
__global__ __launch_bounds__(256, 8) void edge_mlp_f32_kernel(
    const float* __restrict__ input,
    const int*   __restrict__ r_idx,
    const int*   __restrict__ c_idx,
    const float* __restrict__ weight,
    float*       __restrict__ out)
{
    const int lane = threadIdx.x & 63;
    const int wid  = (blockIdx.x * blockDim.x + threadIdx.x) >> 6;
    const int n_waves = (gridDim.x * blockDim.x) >> 6;

    const int d0 = lane * 4;
    const float4 w0 = *(const float4*)(weight + (d0 + 0) * NCLS);
    const float4 w1 = *(const float4*)(weight + (d0 + 1) * NCLS);
    const float4 w2 = *(const float4*)(weight + (d0 + 2) * NCLS);
    const float4 w3 = *(const float4*)(weight + (d0 + 3) * NCLS);

    for (int e = wid; e < EDGES; e += n_waves) {
        const int r = r_idx[e];
        const int c = c_idx[e];
        const float4 a = *(const float4*)(input + (size_t)r * DIM + d0);
        const float4 b = *(const float4*)(input + (size_t)c * DIM + d0);

        const float t0 = fabsf(a.x - b.x);
        const float t1 = fabsf(a.y - b.y);
        const float t2 = fabsf(a.z - b.z);
        const float t3 = fabsf(a.w - b.w);

        float4 acc;
        acc.x = t0 * w0.x + t1 * w1.x + t2 * w2.x + t3 * w3.x;
        acc.y = t0 * w0.y + t1 * w1.y + t2 * w2.y + t3 * w3.y;
        acc.z = t0 * w0.z + t1 * w1.z + t2 * w2.z + t3 * w3.z;
        acc.w = t0 * w0.w + t1 * w1.w + t2 * w2.w + t3 * w3.w;

        #pragma unroll
        for (int m = 32; m >= 1; m >>= 1) {
            acc.x += __shfl_xor(acc.x, m, 64);
            acc.y += __shfl_xor(acc.y, m, 64);
            acc.z += __shfl_xor(acc.z, m, 64);
            acc.w += __shfl_xor(acc.w, m, 64);
        }
        if (lane == 0) *(float4*)(out + (size_t)e * NCLS) = acc;
    }
}

extern "C" void kernel_launch(void* const* d_in, const int* in_sizes, int n_in,
                              void* d_out, int out_size, void* d_ws, size_t ws_size,
                              hipStream_t stream) {
    const float* input  = (const float*)d_in[0];
    const int*   r_idx  = (const int*)d_in[1];
    const int*   c_idx  = (const int*)d_in[2];
    const float* weight = (const float*)d_in[3];
    float* out = (float*)d_out;

    const size_t tbl_bytes   = (size_t)NODES * DIM;                 // 25.6 MB
    const size_t scale_bytes = (size_t)NODES * sizeof(float);       // 0.4 MB
    const size_t rec_off     = (tbl_bytes + scale_bytes + 255) & ~(size_t)255;
    const size_t rec_bytes   = (size_t)EDGES * 16;                  // 8 MB
    const size_t rec_need    = rec_off + rec_bytes;                 // ~34 MB

    if (ws_size >= rec_need) {
        unsigned char* tbl = (unsigned char*)d_ws;
        float* scales = (float*)((char*)d_ws + tbl_bytes);
        uint4* recs   = (uint4*)((char*)d_ws + rec_off);
        quant_kernel<<<2048, 256, 0, stream>>>(input, tbl, scales);
        rec_kernel<<<1954, 256, 0, stream>>>(r_idx, c_idx, scales, recs);
        edge_mlp_i8_rec_kernel<<<2048, 256, 0, stream>>>(tbl, recs, weight, out);
    } else if (ws_size >= tbl_bytes + scale_bytes) {
        unsigned char* tbl = (unsigned char*)d_ws;
        float* scales = (float*)((char*)d_ws + tbl_bytes);
        quant_kernel<<<2048, 256, 0, stream>>>(input, tbl, scales);
        edge_mlp_i8_x2_kernel<<<2048, 256, 0, stream>>>(tbl, scales, r_idx,
                                                        c_idx, weight, out);
    } else {
        edge_mlp_f32_kernel<<<2048, 256, 0, stream>>>(input, r_idx, c_idx,
                                                      weight, out);
    }
}

// Round 11
// 93.518 us; speedup vs baseline: 1.3378x; 1.0508x over previous
//
#include <hip/hip_runtime.h>

// MLPDecoder: out[e, c] = sum_d |input[r[e],d] - input[c[e],d]| * W[d,c]
// N_NODES=100000, D=256, N_EDGES=500000, N_CLASSES=4
//
// R11 = R8 (best: 91.3us total) + convoy-breaking + L2-pollution control.
// R5-R10 established the gather floor (~75us) scales with neither bytes nor
// line count -> lockstep wave convoys queueing on the L2/L3 miss path.
//   delta 1: gather grid 2048 -> 8192 blocks (4 edges/wave-iter, ~4 iters);
//            block turnover staggers wave phases so some waves compute
//            while others' bursts drain.
//   delta 2: nontemporal loads for idx streams, nontemporal stores for out
//            (single-use data; frees ~12MB/dispatch of L2 for the table).
// Math identical to R5-R10: absmax 0.08203125 < 0.143.
// Fallback: fp32 direct if d_ws too small for the 26MB table.

#define NODES   100000
#define DIM     256
#define EDGES   500000   // divisible by 4
#define NCLS    4

typedef float f32x4 __attribute__((ext_vector_type(4)));

// ---------------- k1: per-row quantize to biased uint8 ----------------
__global__ __launch_bounds__(256) void quant_kernel(
    const float* __restrict__ in,        // [NODES, DIM]
    unsigned char* __restrict__ tbl,     // [NODES, DIM] biased uint8
    float* __restrict__ scales)          // [NODES]
{
    const int lane = threadIdx.x & 63;
    const int wid  = (blockIdx.x * blockDim.x + threadIdx.x) >> 6;
    const int n_waves = (gridDim.x * blockDim.x) >> 6;

    for (int row = wid; row < NODES; row += n_waves) {
        const float4 v = *(const float4*)(in + (size_t)row * DIM + lane * 4);
        float m = fmaxf(fmaxf(fabsf(v.x), fabsf(v.y)),
                        fmaxf(fabsf(v.z), fabsf(v.w)));
        #pragma unroll
        for (int s = 32; s >= 1; s >>= 1)
            m = fmaxf(m, __shfl_xor(m, s, 64));

        const float rs = (m > 0.f) ? 127.f / m : 0.f;
        uchar4 q;
        q.x = (unsigned char)__float2int_rn(fmaf(v.x, rs, 128.f));
        q.y = (unsigned char)__float2int_rn(fmaf(v.y, rs, 128.f));
        q.z = (unsigned char)__float2int_rn(fmaf(v.z, rs, 128.f));
        q.w = (unsigned char)__float2int_rn(fmaf(v.w, rs, 128.f));
        *(uchar4*)(tbl + (size_t)row * DIM + lane * 4) = q;

        if (lane == 0) scales[row] = (m > 0.f) ? m / 127.f : 0.f;
    }
}

// ---------------- k2: int8 gather x2-unrolled + skinny matmul ----------------
__global__ __launch_bounds__(256, 6) void edge_mlp_i8_x2_kernel(
    const unsigned char* __restrict__ tbl,   // [NODES, DIM] biased uint8
    const float* __restrict__ scales,        // [NODES]
    const int*   __restrict__ r_idx,         // [EDGES]
    const int*   __restrict__ c_idx,         // [EDGES]
    const float* __restrict__ weight,        // [DIM, NCLS]
    float*       __restrict__ out)           // [EDGES, NCLS]
{
    const int lane = threadIdx.x & 63;
    const int half = lane >> 5;          // which edge of each pair
    const int hl   = lane & 31;          // lane within half
    const int wid  = (blockIdx.x * blockDim.x + threadIdx.x) >> 6;
    const int n_waves = (gridDim.x * blockDim.x) >> 6;
    const int step = n_waves * 4;

    // This lane covers dims [8*hl, 8*hl+8).
    const int d0 = hl * 8;
    float4 w[8];
    #pragma unroll
    for (int j = 0; j < 8; ++j)
        w[j] = *(const float4*)(weight + (d0 + j) * NCLS);

    for (int e = wid * 4; e < EDGES; e += step) {
        // EDGES % 4 == 0 -> e+3 < EDGES whenever e < EDGES.
        const int eeA = e + half;
        const int eeB = e + 2 + half;

        // Streamed single-use index loads: nontemporal (don't pollute L2).
        const int rA = __builtin_nontemporal_load(r_idx + eeA);
        const int cA = __builtin_nontemporal_load(c_idx + eeA);
        const int rB = __builtin_nontemporal_load(r_idx + eeB);
        const int cB = __builtin_nontemporal_load(c_idx + eeB);

        const float srA = scales[rA], scA = scales[cA];
        const float srB = scales[rB], scB = scales[cB];
        const uint2 uaA = *(const uint2*)(tbl + (size_t)rA * DIM + d0);
        const uint2 ubA = *(const uint2*)(tbl + (size_t)cA * DIM + d0);
        const uint2 uaB = *(const uint2*)(tbl + (size_t)rB * DIM + d0);
        const uint2 ubB = *(const uint2*)(tbl + (size_t)cB * DIM + d0);

        float u, t;
        #define TERM(UA, UB, SH, W, SR, NSC, BB, ACC)                        \
            u = fmaf((float)((UA >> SH) & 0xffu), SR,                        \
                     fmaf((float)((UB >> SH) & 0xffu), NSC, BB));            \
            t = fabsf(u);                                                    \
            ACC.x = fmaf(t, W.x, ACC.x);                                     \
            ACC.y = fmaf(t, W.y, ACC.y);                                     \
            ACC.z = fmaf(t, W.z, ACC.z);                                     \
            ACC.w = fmaf(t, W.w, ACC.w);

        const float nscA = -scA;
        const float BA = 128.f * (scA - srA);
        float4 accA = make_float4(0.f, 0.f, 0.f, 0.f);
        TERM(uaA.x, ubA.x,  0, w[0], srA, nscA, BA, accA)
        TERM(uaA.x, ubA.x,  8, w[1], srA, nscA, BA, accA)
        TERM(uaA.x, ubA.x, 16, w[2], srA, nscA, BA, accA)
        TERM(uaA.x, ubA.x, 24, w[3], srA, nscA, BA, accA)
        TERM(uaA.y, ubA.y,  0, w[4], srA, nscA, BA, accA)
        TERM(uaA.y, ubA.y,  8, w[5], srA, nscA, BA, accA)
        TERM(uaA.y, ubA.y, 16, w[6], srA, nscA, BA, accA)
        TERM(uaA.y, ubA.y, 24, w[7], srA, nscA, BA, accA)

        const float nscB = -scB;
        const float BB = 128.f * (scB - srB);
        float4 accB = make_float4(0.f, 0.f, 0.f, 0.f);
        TERM(uaB.x, ubB.x,  0, w[0], srB, nscB, BB, accB)
        TERM(uaB.x, ubB.x,  8, w[1], srB, nscB, BB, accB)
        TERM(uaB.x, ubB.x, 16, w[2], srB, nscB, BB, accB)
        TERM(uaB.x, ubB.x, 24, w[3], srB, nscB, BB, accB)
        TERM(uaB.y, ubB.y,  0, w[4], srB, nscB, BB, accB)
        TERM(uaB.y, ubB.y,  8, w[5], srB, nscB, BB, accB)
        TERM(uaB.y, ubB.y, 16, w[6], srB, nscB, BB, accB)
        TERM(uaB.y, ubB.y, 24, w[7], srB, nscB, BB, accB)
        #undef TERM

        // Two interleaved butterflies within each 32-lane half.
        #pragma unroll
        for (int m = 16; m >= 1; m >>= 1) {
            accA.x += __shfl_xor(accA.x, m, 64);
            accB.x += __shfl_xor(accB.x, m, 64);
            accA.y += __shfl_xor(accA.y, m, 64);
            accB.y += __shfl_xor(accB.y, m, 64);
            accA.z += __shfl_xor(accA.z, m, 64);
            accB.z += __shfl_xor(accB.z, m, 64);
            accA.w += __shfl_xor(accA.w, m, 64);
            accB.w += __shfl_xor(accB.w, m, 64);
        }

        if (hl == 0) {
            // Single-use output: nontemporal store (keep L2 for the table).
            f32x4 vA, vB;
            vA.x = accA.x; vA.y = accA.y; vA.z = accA.z; vA.w = accA.w;
            vB.x = accB.x; vB.y = accB.y; vB.z = accB.z; vB.w = accB.w;
            __builtin_nontemporal_store(vA, (f32x4*)(out + (size_t)eeA * NCLS));
            __builtin_nontemporal_store(vB, (f32x4*)(out + (size_t)eeB * NCLS));
        }
    }
}

// ---------------- fallback: fp32 wave-per-edge (proven R1) ----------------
__global__ __launch_bounds__(256, 8) void edge_mlp_f32_kernel(
    const float* __restrict__ input,
    const int*   __restrict__ r_idx,
    const int*   __restrict__ c_idx,
    const float* __restrict__ weight,
    float*       __restrict__ out)
{
    const int lane = threadIdx.x & 63;
    const int wid  = (blockIdx.x * blockDim.x + threadIdx.x) >> 6;
    const int n_waves = (gridDim.x * blockDim.x) >> 6;

    const int d0 = lane * 4;
    const float4 w0 = *(const float4*)(weight + (d0 + 0) * NCLS);
    const float4 w1 = *(const float4*)(weight + (d0 + 1) * NCLS);
    const float4 w2 = *(const float4*)(weight + (d0 + 2) * NCLS);
    const float4 w3 = *(const float4*)(weight + (d0 + 3) * NCLS);

    for (int e = wid; e < EDGES; e += n_waves) {
        const int r = r_idx[e];
        const int c = c_idx[e];
        const float4 a = *(const float4*)(input + (size_t)r * DIM + d0);
        const float4 b = *(const float4*)(input + (size_t)c * DIM + d0);

        const float t0 = fabsf(a.x - b.x);
        const float t1 = fabsf(a.y - b.y);
        const float t2 = fabsf(a.z - b.z);
        const float t3 = fabsf(a.w - b.w);

        float4 acc;
        acc.x = t0 * w0.x + t1 * w1.x + t2 * w2.x + t3 * w3.x;
        acc.y = t0 * w0.y + t1 * w1.y + t2 * w2.y + t3 * w3.y;
        acc.z = t0 * w0.z + t1 * w1.z + t2 * w2.z + t3 * w3.z;
        acc.w = t0 * w0.w + t1 * w1.w + t2 * w2.w + t3 * w3.w;

        #pragma unroll
        for (int m = 32; m >= 1; m >>= 1) {
            acc.x += __shfl_xor(acc.x, m, 64);
            acc.y += __shfl_xor(acc.y, m, 64);
            acc.z += __shfl_xor(acc.z, m, 64);
            acc.w += __shfl_xor(acc.w, m, 64);
        }
        if (lane == 0) *(float4*)(out + (size_t)e * NCLS) = acc;
    }
}

extern "C" void kernel_launch(void* const* d_in, const int* in_sizes, int n_in,
                              void* d_out, int out_size, void* d_ws, size_t ws_size,
                              hipStream_t stream) {
    const float* input  = (const float*)d_in[0];
    const int*   r_idx  = (const int*)d_in[1];
    const int*   c_idx  = (const int*)d_in[2];
    const float* weight = (const float*)d_in[3];
    float* out = (float*)d_out;

    const size_t tbl_bytes   = (size_t)NODES * DIM;           // 25.6 MB uint8
    const size_t scale_bytes = (size_t)NODES * sizeof(float); // 0.4 MB

    if (ws_size >= tbl_bytes + scale_bytes) {
        unsigned char* tbl = (unsigned char*)d_ws;
        float* scales = (float*)((char*)d_ws + tbl_bytes);
        quant_kernel<<<2048, 256, 0, stream>>>(input, tbl, scales);
        // 8192 blocks: ~4 iterations/wave; block turnover staggers wave
        // phases so load bursts and compute overlap across blocks.
        edge_mlp_i8_x2_kernel<<<8192, 256, 0, stream>>>(tbl, scales, r_idx,
                                                        c_idx, weight, out);
    } else {
        edge_mlp_f32_kernel<<<2048, 256, 0, stream>>>(input, r_idx, c_idx,
                                                      weight, out);
    }
}

// Round 12
// 91.112 us; speedup vs baseline: 1.3732x; 1.0264x over previous
//
#include <hip/hip_runtime.h>

// MLPDecoder: out[e, c] = sum_d |input[r[e],d] - input[c[e],d]| * W[d,c]
// N_NODES=100000, D=256, N_EDGES=500000, N_CLASSES=4
//
// R12 (terminal) = R8 exact config, the measured best (91.3us total).
// Ledger of falsified levers on the ~75us gather floor:
//   bytes/2 (bf16->int8): -5% | pipelining: -27% | x2 ILP: +5%
//   L2-slice residency: -37% net | chain-shortening (recs): -7% net
//   convoy-break (8192 blk): -2% | nontemporal hints: 0%
// Line-rate arithmetic: R1/R4 were line-BW-bound (~6 TB/s L2-side, time
// proportional to lines); at int8 (2M lines) the time decoupled from lines
// AND bytes -> structural per-edge service bound (~38ns/edge/CU).
// Floor: quant ~16-20us (stream roofline on 128MB) + gather ~75us == ~91us.
//   k1: per-row absmax -> biased uint8 quantize, scale[row] = m/127.
//   k2: half-wave per edge, lane = 8 dims via uint2; 4 edges/wave-iter,
//       batched independent loads; 5-stage interleaved butterflies.
// absmax 0.08203125 < 0.143 threshold (measured, rounds 5-11).
// Fallback: fp32 direct kernel if d_ws too small.

#define NODES   100000
#define DIM     256
#define EDGES   500000   // divisible by 4
#define NCLS    4

// ---------------- k1: per-row quantize to biased uint8 ----------------
__global__ __launch_bounds__(256) void quant_kernel(
    const float* __restrict__ in,        // [NODES, DIM]
    unsigned char* __restrict__ tbl,     // [NODES, DIM] biased uint8
    float* __restrict__ scales)          // [NODES]
{
    const int lane = threadIdx.x & 63;
    const int wid  = (blockIdx.x * blockDim.x + threadIdx.x) >> 6;
    const int n_waves = (gridDim.x * blockDim.x) >> 6;

    for (int row = wid; row < NODES; row += n_waves) {
        const float4 v = *(const float4*)(in + (size_t)row * DIM + lane * 4);
        float m = fmaxf(fmaxf(fabsf(v.x), fabsf(v.y)),
                        fmaxf(fabsf(v.z), fabsf(v.w)));
        #pragma unroll
        for (int s = 32; s >= 1; s >>= 1)
            m = fmaxf(m, __shfl_xor(m, s, 64));

        const float rs = (m > 0.f) ? 127.f / m : 0.f;
        uchar4 q;
        q.x = (unsigned char)__float2int_rn(fmaf(v.x, rs, 128.f));
        q.y = (unsigned char)__float2int_rn(fmaf(v.y, rs, 128.f));
        q.z = (unsigned char)__float2int_rn(fmaf(v.z, rs, 128.f));
        q.w = (unsigned char)__float2int_rn(fmaf(v.w, rs, 128.f));
        *(uchar4*)(tbl + (size_t)row * DIM + lane * 4) = q;

        if (lane == 0) scales[row] = (m > 0.f) ? m / 127.f : 0.f;
    }
}

// ---------------- k2: int8 gather x2-unrolled + skinny matmul ----------------
__global__ __launch_bounds__(256, 6) void edge_mlp_i8_x2_kernel(
    const unsigned char* __restrict__ tbl,   // [NODES, DIM] biased uint8
    const float* __restrict__ scales,        // [NODES]
    const int*   __restrict__ r_idx,         // [EDGES]
    const int*   __restrict__ c_idx,         // [EDGES]
    const float* __restrict__ weight,        // [DIM, NCLS]
    float*       __restrict__ out)           // [EDGES, NCLS]
{
    const int lane = threadIdx.x & 63;
    const int half = lane >> 5;          // which edge of each pair
    const int hl   = lane & 31;          // lane within half
    const int wid  = (blockIdx.x * blockDim.x + threadIdx.x) >> 6;
    const int n_waves = (gridDim.x * blockDim.x) >> 6;
    const int step = n_waves * 4;

    // This lane covers dims [8*hl, 8*hl+8).
    const int d0 = hl * 8;
    float4 w[8];
    #pragma unroll
    for (int j = 0; j < 8; ++j)
        w[j] = *(const float4*)(weight + (d0 + j) * NCLS);

    for (int e = wid * 4; e < EDGES; e += step) {
        // EDGES % 4 == 0 -> e+3 < EDGES whenever e < EDGES.
        const int eeA = e + half;
        const int eeB = e + 2 + half;

        // ---- Batch of independent loads: 4 idx pairs, then scales+rows ----
        const int rA = r_idx[eeA], cA = c_idx[eeA];
        const int rB = r_idx[eeB], cB = c_idx[eeB];

        const float srA = scales[rA], scA = scales[cA];
        const float srB = scales[rB], scB = scales[cB];
        const uint2 uaA = *(const uint2*)(tbl + (size_t)rA * DIM + d0);
        const uint2 ubA = *(const uint2*)(tbl + (size_t)cA * DIM + d0);
        const uint2 uaB = *(const uint2*)(tbl + (size_t)rB * DIM + d0);
        const uint2 ubB = *(const uint2*)(tbl + (size_t)cB * DIM + d0);

        float u, t;
        #define TERM(UA, UB, SH, W, SR, NSC, BB, ACC)                        \
            u = fmaf((float)((UA >> SH) & 0xffu), SR,                        \
                     fmaf((float)((UB >> SH) & 0xffu), NSC, BB));            \
            t = fabsf(u);                                                    \
            ACC.x = fmaf(t, W.x, ACC.x);                                     \
            ACC.y = fmaf(t, W.y, ACC.y);                                     \
            ACC.z = fmaf(t, W.z, ACC.z);                                     \
            ACC.w = fmaf(t, W.w, ACC.w);

        const float nscA = -scA;
        const float BA = 128.f * (scA - srA);
        float4 accA = make_float4(0.f, 0.f, 0.f, 0.f);
        TERM(uaA.x, ubA.x,  0, w[0], srA, nscA, BA, accA)
        TERM(uaA.x, ubA.x,  8, w[1], srA, nscA, BA, accA)
        TERM(uaA.x, ubA.x, 16, w[2], srA, nscA, BA, accA)
        TERM(uaA.x, ubA.x, 24, w[3], srA, nscA, BA, accA)
        TERM(uaA.y, ubA.y,  0, w[4], srA, nscA, BA, accA)
        TERM(uaA.y, ubA.y,  8, w[5], srA, nscA, BA, accA)
        TERM(uaA.y, ubA.y, 16, w[6], srA, nscA, BA, accA)
        TERM(uaA.y, ubA.y, 24, w[7], srA, nscA, BA, accA)

        const float nscB = -scB;
        const float BB = 128.f * (scB - srB);
        float4 accB = make_float4(0.f, 0.f, 0.f, 0.f);
        TERM(uaB.x, ubB.x,  0, w[0], srB, nscB, BB, accB)
        TERM(uaB.x, ubB.x,  8, w[1], srB, nscB, BB, accB)
        TERM(uaB.x, ubB.x, 16, w[2], srB, nscB, BB, accB)
        TERM(uaB.x, ubB.x, 24, w[3], srB, nscB, BB, accB)
        TERM(uaB.y, ubB.y,  0, w[4], srB, nscB, BB, accB)
        TERM(uaB.y, ubB.y,  8, w[5], srB, nscB, BB, accB)
        TERM(uaB.y, ubB.y, 16, w[6], srB, nscB, BB, accB)
        TERM(uaB.y, ubB.y, 24, w[7], srB, nscB, BB, accB)
        #undef TERM

        // ---- Interleaved butterflies (two independent shfl chains) ----
        #pragma unroll
        for (int m = 16; m >= 1; m >>= 1) {
            accA.x += __shfl_xor(accA.x, m, 64);
            accB.x += __shfl_xor(accB.x, m, 64);
            accA.y += __shfl_xor(accA.y, m, 64);
            accB.y += __shfl_xor(accB.y, m, 64);
            accA.z += __shfl_xor(accA.z, m, 64);
            accB.z += __shfl_xor(accB.z, m, 64);
            accA.w += __shfl_xor(accA.w, m, 64);
            accB.w += __shfl_xor(accB.w, m, 64);
        }

        if (hl == 0) {
            *(float4*)(out + (size_t)eeA * NCLS) = accA;
            *(float4*)(out + (size_t)eeB * NCLS) = accB;
        }
    }
}

// ---------------- fallback: fp32 wave-per-edge (proven R1) ----------------
__global__ __launch_bounds__(256, 8) void edge_mlp_f32_kernel(
    const float* __restrict__ input,
    const int*   __restrict__ r_idx,
    const int*   __restrict__ c_idx,
    const float* __restrict__ weight,
    float*       __restrict__ out)
{
    const int lane = threadIdx.x & 63;
    const int wid  = (blockIdx.x * blockDim.x + threadIdx.x) >> 6;
    const int n_waves = (gridDim.x * blockDim.x) >> 6;

    const int d0 = lane * 4;
    const float4 w0 = *(const float4*)(weight + (d0 + 0) * NCLS);
    const float4 w1 = *(const float4*)(weight + (d0 + 1) * NCLS);
    const float4 w2 = *(const float4*)(weight + (d0 + 2) * NCLS);
    const float4 w3 = *(const float4*)(weight + (d0 + 3) * NCLS);

    for (int e = wid; e < EDGES; e += n_waves) {
        const int r = r_idx[e];
        const int c = c_idx[e];
        const float4 a = *(const float4*)(input + (size_t)r * DIM + d0);
        const float4 b = *(const float4*)(input + (size_t)c * DIM + d0);

        const float t0 = fabsf(a.x - b.x);
        const float t1 = fabsf(a.y - b.y);
        const float t2 = fabsf(a.z - b.z);
        const float t3 = fabsf(a.w - b.w);

        float4 acc;
        acc.x = t0 * w0.x + t1 * w1.x + t2 * w2.x + t3 * w3.x;
        acc.y = t0 * w0.y + t1 * w1.y + t2 * w2.y + t3 * w3.y;
        acc.z = t0 * w0.z + t1 * w1.z + t2 * w2.z + t3 * w3.z;
        acc.w = t0 * w0.w + t1 * w1.w + t2 * w2.w + t3 * w3.w;

        #pragma unroll
        for (int m = 32; m >= 1; m >>= 1) {
            acc.x += __shfl_xor(acc.x, m, 64);
            acc.y += __shfl_xor(acc.y, m, 64);
            acc.z += __shfl_xor(acc.z, m, 64);
            acc.w += __shfl_xor(acc.w, m, 64);
        }
        if (lane == 0) *(float4*)(out + (size_t)e * NCLS) = acc;
    }
}

extern "C" void kernel_launch(void* const* d_in, const int* in_sizes, int n_in,
                              void* d_out, int out_size, void* d_ws, size_t ws_size,
                              hipStream_t stream) {
    const float* input  = (const float*)d_in[0];
    const int*   r_idx  = (const int*)d_in[1];
    const int*   c_idx  = (const int*)d_in[2];
    const float* weight = (const float*)d_in[3];
    float* out = (float*)d_out;

    const size_t tbl_bytes   = (size_t)NODES * DIM;           // 25.6 MB uint8
    const size_t scale_bytes = (size_t)NODES * sizeof(float); // 0.4 MB

    if (ws_size >= tbl_bytes + scale_bytes) {
        unsigned char* tbl = (unsigned char*)d_ws;
        float* scales = (float*)((char*)d_ws + tbl_bytes);
        quant_kernel<<<2048, 256, 0, stream>>>(input, tbl, scales);
        edge_mlp_i8_x2_kernel<<<2048, 256, 0, stream>>>(tbl, scales, r_idx,
                                                        c_idx, weight, out);
    } else {
        edge_mlp_f32_kernel<<<2048, 256, 0, stream>>>(input, r_idx, c_idx,
                                                      weight, out);
    }
}